// Round 2
// baseline (222.717 us; speedup 1.0000x reference)
//
#include <hip/hip_runtime.h>
#include <hip/hip_bf16.h>

typedef __bf16 bf16_t;
typedef __bf16 bf16x4 __attribute__((ext_vector_type(4)));
typedef __bf16 bf16x8 __attribute__((ext_vector_type(8)));
typedef float f32x4 __attribute__((ext_vector_type(4)));

#define IN_DIM 21
#define HID 512
#define OUT_DIM 21
#define M_TILE 64
#define THREADS 512   // 8 waves; LDS ~70 KB -> 2 blocks/CU (16 waves/CU, cross-block overlap)

// XOR swizzle in element units: flips col bits 3..5 with row low bits.
// For all h accesses row&7 == l16&7 (row = mt*16 + l16), so the XOR term is a
// per-lane constant. b128 reads and b64 writes stay aligned (XOR touches
// bits >= 3 only) and land 2-way max per bank (free per m136).
__device__ __forceinline__ int swz(int row, int col) {
    return col ^ ((row & 7) << 3);
}

// ---- prep: convert weights fp32 -> bf16 *fragment-major* layouts in ws ----
// Fragment for 16x16x32 mfma (identical per-lane mapping for A and B roles):
// element (outer = tile*16 + (lane&15), k = k0 + (lane>>4)*8 + j) stored at
// frag_base + lane*8 + j -> wave load is contiguous 1 KB.
// W2f: [kstep(16)][ntile(32)][512]   W1f: [ntile(32)][512] (k>=21 zero)
// W3f: [kstep(16)][otile(2)][512]    (o>=21 zero)
__global__ void prep_kernel(const float* __restrict__ W1, const float* __restrict__ W2,
                            const float* __restrict__ W3,
                            bf16_t* __restrict__ W1f, bf16_t* __restrict__ W2f,
                            bf16_t* __restrict__ W3f) {
    int i = blockIdx.x * blockDim.x + threadIdx.x;
    int stride = gridDim.x * blockDim.x;
    const int NW2 = HID * HID;     // 262144
    const int NW1 = 32 * 512;      // 16384
    const int NW3 = 16 * 2 * 512;  // 16384
    for (; i < NW2 + NW1 + NW3; i += stride) {
        if (i < NW2) {
            int j = i & 7, lane = (i >> 3) & 63, ntile = (i >> 9) & 31, kstep = i >> 14;
            int n = ntile * 16 + (lane & 15);
            int k = kstep * 32 + (lane >> 4) * 8 + j;
            W2f[i] = (bf16_t)W2[n * HID + k];
        } else if (i < NW2 + NW1) {
            int t = i - NW2;
            int j = t & 7, lane = (t >> 3) & 63, ntile = t >> 9;
            int n = ntile * 16 + (lane & 15);
            int k = (lane >> 4) * 8 + j;
            W1f[t] = (k < IN_DIM) ? (bf16_t)W1[n * IN_DIM + k] : (bf16_t)0.0f;
        } else {
            int t = i - NW2 - NW1;
            int j = t & 7, lane = (t >> 3) & 63, ot = (t >> 9) & 1, kstep = t >> 10;
            int o = ot * 16 + (lane & 15);
            int k = kstep * 32 + (lane >> 4) * 8 + j;
            W3f[t] = (o < OUT_DIM) ? (bf16_t)W3[o * HID + k] : (bf16_t)0.0f;
        }
    }
}

// ---- fused MLP + loss ----
// Operand-swapped mfma everywhere: D = A(W-frag) * B(activation^T-frag), so
// D col = lane&15 = batch-row m, D row = quad*4+r = feature n. Each lane's 4
// accumulator values are 4 CONSECUTIVE features of one batch row -> epilogue
// is one ds_write_b64, biases are aligned float4, gt reads hit one line.
__global__ __launch_bounds__(THREADS, 4)  // 4 waves/EU -> VGPR cap 128, 2 blocks/CU
void fused_kernel(const float* __restrict__ V, const float* __restrict__ gt,
                  const float* __restrict__ b1, const float* __restrict__ b2,
                  const float* __restrict__ b3,
                  const bf16_t* __restrict__ W1f, const bf16_t* __restrict__ W2f,
                  const bf16_t* __restrict__ W3f, float* __restrict__ accum) {
    __shared__ __align__(16) bf16_t vlds[M_TILE][40];  // stride 80 B: b128 reads 2-way max
    __shared__ __align__(16) bf16_t h[M_TILE][HID];    // single buffer: h1, then h2 in-place
    __shared__ float redbuf[16];

    const int tid  = threadIdx.x;
    const int wave = tid >> 6;       // 0..7
    const int lane = tid & 63;
    const int quad = lane >> 4;
    const int l16  = lane & 15;
    const int sx   = (l16 & 7) << 3; // per-lane swizzle XOR constant (row&7 == l16&7)
    const long row0 = (long)blockIdx.x * M_TILE;

    // phase 0: velocities tile -> LDS bf16, k padded to 32 with zeros
    for (int idx = tid; idx < M_TILE * 32; idx += THREADS) {
        int r = idx >> 5, c = idx & 31;
        float v = (c < IN_DIM) ? V[(row0 + r) * IN_DIM + c] : 0.0f;
        vlds[r][c] = (bf16_t)v;
    }
    __syncthreads();

    // phase 1: h1[m][n] = relu(V @ W1^T + b1), n in [wave*64, wave*64+64)
    {
        bf16x8 bv[4];
        #pragma unroll
        for (int mt = 0; mt < 4; ++mt)
            bv[mt] = *reinterpret_cast<const bf16x8*>(&vlds[mt * 16 + l16][quad * 8]);
        #pragma unroll
        for (int nt = 0; nt < 4; ++nt) {
            int ntile = wave * 4 + nt;
            bf16x8 aw = *reinterpret_cast<const bf16x8*>(W1f + ntile * 512 + lane * 8);
            f32x4 bias = *reinterpret_cast<const f32x4*>(b1 + ntile * 16 + quad * 4);
            int n0 = ntile * 16 + quad * 4;
            #pragma unroll
            for (int mt = 0; mt < 4; ++mt) {
                f32x4 c = {0.0f, 0.0f, 0.0f, 0.0f};
                c = __builtin_amdgcn_mfma_f32_16x16x32_bf16(aw, bv[mt], c, 0, 0, 0);
                bf16x4 pk;
                #pragma unroll
                for (int r = 0; r < 4; ++r) {
                    float v = c[r] + bias[r];
                    pk[r] = (bf16_t)(v > 0.0f ? v : 0.0f);
                }
                int m = mt * 16 + l16;
                *reinterpret_cast<bf16x4*>(&h[m][n0 ^ sx]) = pk;
            }
        }
    }
    __syncthreads();

    // phase 2: h2 = relu(h1 @ W2^T + b2). Per wave: M=64, N=64, K=512.
    // acc holds the whole per-wave output through the barrier, then h is
    // overwritten in place (single LDS buffer).
    {
        f32x4 acc[4][4];
        #pragma unroll
        for (int mt = 0; mt < 4; ++mt)
            #pragma unroll
            for (int nt = 0; nt < 4; ++nt)
                acc[mt][nt] = (f32x4){0.0f, 0.0f, 0.0f, 0.0f};

        const bf16_t* w2p = W2f + (wave * 4) * 512 + lane * 8;  // + nt*512 + ks*16384

        #pragma unroll
        for (int ks = 0; ks < 16; ++ks) {
            bf16x8 bh[4];
            #pragma unroll
            for (int mt = 0; mt < 4; ++mt)
                bh[mt] = *reinterpret_cast<const bf16x8*>(
                    &h[mt * 16 + l16][(ks * 32 + quad * 8) ^ sx]);
            bf16x8 aw[4];
            #pragma unroll
            for (int nt = 0; nt < 4; ++nt)
                aw[nt] = *reinterpret_cast<const bf16x8*>(w2p + ks * 16384 + nt * 512);
            #pragma unroll
            for (int mt = 0; mt < 4; ++mt)
                #pragma unroll
                for (int nt = 0; nt < 4; ++nt)
                    acc[mt][nt] = __builtin_amdgcn_mfma_f32_16x16x32_bf16(aw[nt], bh[mt], acc[mt][nt], 0, 0, 0);
        }
        __syncthreads();  // all reads of h1 complete before overwrite

        #pragma unroll
        for (int nt = 0; nt < 4; ++nt) {
            int ntile = wave * 4 + nt;
            f32x4 bias = *reinterpret_cast<const f32x4*>(b2 + ntile * 16 + quad * 4);
            int n0 = ntile * 16 + quad * 4;
            #pragma unroll
            for (int mt = 0; mt < 4; ++mt) {
                bf16x4 pk;
                #pragma unroll
                for (int r = 0; r < 4; ++r) {
                    float v = acc[mt][nt][r] + bias[r];
                    pk[r] = (bf16_t)(v > 0.0f ? v : 0.0f);
                }
                int m = mt * 16 + l16;
                *reinterpret_cast<bf16x4*>(&h[m][n0 ^ sx]) = pk;
            }
        }
    }
    __syncthreads();

    // phase 3: out = h2 @ W3^T + b3, then loss. 8 jobs = 4 mt x 2 ot = 8 waves.
    {
        const int mt = wave >> 1;
        const int ot = wave & 1;
        const int o0 = ot * 16 + quad * 4;
        const long grow = row0 + mt * 16 + l16;

        // hoist gt/b3 loads above the K-loop (hide latency under MFMAs)
        float g[4], b3v[4];
        #pragma unroll
        for (int r = 0; r < 4; ++r) {
            bool v = (o0 + r) < OUT_DIM;
            g[r]   = v ? gt[grow * OUT_DIM + o0 + r] : -10000.0f;
            b3v[r] = v ? b3[o0 + r] : 0.0f;
        }

        f32x4 acc3a = {0.0f, 0.0f, 0.0f, 0.0f};
        f32x4 acc3b = {0.0f, 0.0f, 0.0f, 0.0f};
        const int rr = mt * 16 + l16;
        #pragma unroll
        for (int ks = 0; ks < 16; ks += 2) {
            bf16x8 bh0 = *reinterpret_cast<const bf16x8*>(&h[rr][(ks * 32 + quad * 8) ^ sx]);
            bf16x8 bh1 = *reinterpret_cast<const bf16x8*>(&h[rr][((ks + 1) * 32 + quad * 8) ^ sx]);
            bf16x8 aw0 = *reinterpret_cast<const bf16x8*>(W3f + (ks * 2 + ot) * 512 + lane * 8);
            bf16x8 aw1 = *reinterpret_cast<const bf16x8*>(W3f + ((ks + 1) * 2 + ot) * 512 + lane * 8);
            acc3a = __builtin_amdgcn_mfma_f32_16x16x32_bf16(aw0, bh0, acc3a, 0, 0, 0);
            acc3b = __builtin_amdgcn_mfma_f32_16x16x32_bf16(aw1, bh1, acc3b, 0, 0, 0);
        }

        float num = 0.0f, den = 0.0f;
        #pragma unroll
        for (int r = 0; r < 4; ++r) {
            if ((o0 + r) < OUT_DIM) {
                float pred = acc3a[r] + acc3b[r] + b3v[r];
                if (g[r] > -5000.0f) {
                    float w = (floorf(pred * 2.0f) == floorf(g[r] * 2.0f)) ? 0.5f : 1.0f;
                    num += fabsf(pred * w - g[r] * w);
                    den += 1.0f;
                }
            }
        }
        #pragma unroll
        for (int off = 32; off > 0; off >>= 1) {
            num += __shfl_down(num, off);
            den += __shfl_down(den, off);
        }
        if (lane == 0) { redbuf[wave * 2] = num; redbuf[wave * 2 + 1] = den; }
    }
    __syncthreads();
    if (tid == 0) {
        float n8 = 0.0f, d8 = 0.0f;
        #pragma unroll
        for (int w = 0; w < 8; ++w) { n8 += redbuf[w * 2]; d8 += redbuf[w * 2 + 1]; }
        atomicAdd(accum, n8);
        atomicAdd(accum + 1, d8);
    }
}

__global__ void finalize_kernel(const float* __restrict__ accum, float* __restrict__ out) {
    if (threadIdx.x == 0) out[0] = accum[0] / accum[1];
}

extern "C" void kernel_launch(void* const* d_in, const int* in_sizes, int n_in,
                              void* d_out, int out_size, void* d_ws, size_t ws_size,
                              hipStream_t stream) {
    const float* V  = (const float*)d_in[0];
    const float* gt = (const float*)d_in[1];
    const float* W1 = (const float*)d_in[2];
    const float* b1 = (const float*)d_in[3];
    const float* W2 = (const float*)d_in[4];
    const float* b2 = (const float*)d_in[5];
    const float* W3 = (const float*)d_in[6];
    const float* b3 = (const float*)d_in[7];
    float* out = (float*)d_out;

    char* ws = (char*)d_ws;
    float* accum = (float*)ws;                                       // 2 floats
    bf16_t* W2f = (bf16_t*)(ws + 16);                                // 512 KB
    bf16_t* W1f = (bf16_t*)(ws + 16 + 512 * 512 * 2);                // 32 KB
    bf16_t* W3f = (bf16_t*)(ws + 16 + 512 * 512 * 2 + 32 * 512 * 2); // 32 KB

    int Brows = in_sizes[0] / IN_DIM;   // 131072
    int grid = Brows / M_TILE;          // 2048

    hipMemsetAsync(accum, 0, 2 * sizeof(float), stream);
    prep_kernel<<<576, 512, 0, stream>>>(W1, W2, W3, W1f, W2f, W3f);
    fused_kernel<<<grid, THREADS, 0, stream>>>(V, gt, b1, b2, b3, W1f, W2f, W3f, accum);
    finalize_kernel<<<1, 64, 0, stream>>>(accum, out);
}

// Round 3
// 194.580 us; speedup vs baseline: 1.1446x; 1.1446x over previous
//
#include <hip/hip_runtime.h>
#include <hip/hip_bf16.h>

typedef __bf16 bf16_t;
typedef __bf16 bf16x4 __attribute__((ext_vector_type(4)));
typedef __bf16 bf16x8 __attribute__((ext_vector_type(8)));
typedef float f32x4 __attribute__((ext_vector_type(4)));

#define IN_DIM 21
#define HID 512
#define OUT_DIM 21
#define M_TILE 64
#define THREADS 512   // 8 waves; LDS ~70 KB -> 2 blocks/CU (16 waves/CU, cross-block overlap)

// XOR swizzle in element units: flips col bits 3..5 with row low bits.
// For all h accesses row&7 == l16&7 (row = mt*16 + l16), so the XOR term is a
// per-lane constant. b128 reads and b64 writes stay aligned (XOR touches
// bits >= 3 only) and land 2-way max per bank (free per m136).
__device__ __forceinline__ int swz(int row, int col) {
    return col ^ ((row & 7) << 3);
}

// ---- prep: convert weights fp32 -> bf16 *fragment-major* layouts in ws ----
// Fragment for 16x16x32 mfma (identical per-lane mapping for A and B roles):
// element (outer = tile*16 + (lane&15), k = k0 + (lane>>4)*8 + j) stored at
// frag_base + lane*8 + j -> wave load is contiguous 1 KB.
// W2f: [kstep(16)][ntile(32)][512]   W1f: [ntile(32)][512] (k>=21 zero)
// W3f: [kstep(16)][otile(2)][512]    (o>=21 zero)
__global__ void prep_kernel(const float* __restrict__ W1, const float* __restrict__ W2,
                            const float* __restrict__ W3,
                            bf16_t* __restrict__ W1f, bf16_t* __restrict__ W2f,
                            bf16_t* __restrict__ W3f, float* __restrict__ accum) {
    if (blockIdx.x == 0 && threadIdx.x == 0) { accum[0] = 0.0f; accum[1] = 0.0f; }
    int i = blockIdx.x * blockDim.x + threadIdx.x;
    int stride = gridDim.x * blockDim.x;
    const int NW2 = HID * HID;     // 262144
    const int NW1 = 32 * 512;      // 16384
    const int NW3 = 16 * 2 * 512;  // 16384
    for (; i < NW2 + NW1 + NW3; i += stride) {
        if (i < NW2) {
            int j = i & 7, lane = (i >> 3) & 63, ntile = (i >> 9) & 31, kstep = i >> 14;
            int n = ntile * 16 + (lane & 15);
            int k = kstep * 32 + (lane >> 4) * 8 + j;
            W2f[i] = (bf16_t)W2[n * HID + k];
        } else if (i < NW2 + NW1) {
            int t = i - NW2;
            int j = t & 7, lane = (t >> 3) & 63, ntile = t >> 9;
            int n = ntile * 16 + (lane & 15);
            int k = (lane >> 4) * 8 + j;
            W1f[t] = (k < IN_DIM) ? (bf16_t)W1[n * IN_DIM + k] : (bf16_t)0.0f;
        } else {
            int t = i - NW2 - NW1;
            int j = t & 7, lane = (t >> 3) & 63, ot = (t >> 9) & 1, kstep = t >> 10;
            int o = ot * 16 + (lane & 15);
            int k = kstep * 32 + (lane >> 4) * 8 + j;
            W3f[t] = (o < OUT_DIM) ? (bf16_t)W3[o * HID + k] : (bf16_t)0.0f;
        }
    }
}

// ---- fused MLP + loss ----
// Operand-swapped mfma everywhere: D = A(W-frag) * B(activation^T-frag), so
// D col = lane&15 = batch-row m, D row = quad*4+r = feature n. Each lane's 4
// accumulator values are 4 CONSECUTIVE features of one batch row -> epilogue
// is one ds_write_b64, biases are aligned float4, gt reads hit one line.
__global__ __launch_bounds__(THREADS, 4)  // 4 waves/EU -> reg cap 128 (64 arch + 64 acc)
void fused_kernel(const float* __restrict__ V, const float* __restrict__ gt,
                  const float* __restrict__ b1, const float* __restrict__ b2,
                  const float* __restrict__ b3,
                  const bf16_t* __restrict__ W1f, const bf16_t* __restrict__ W2f,
                  const bf16_t* __restrict__ W3f, float* __restrict__ accum) {
    __shared__ __align__(16) bf16_t vlds[M_TILE][40];  // stride 80 B: b128 reads 2-way max
    __shared__ __align__(16) bf16_t h[M_TILE][HID];    // single buffer: h1, then h2 in-place
    __shared__ float redbuf[16];

    const int tid  = threadIdx.x;
    const int wave = tid >> 6;       // 0..7
    const int lane = tid & 63;
    const int quad = lane >> 4;
    const int l16  = lane & 15;
    const int sx   = (l16 & 7) << 3; // per-lane swizzle XOR constant (row&7 == l16&7)
    const long row0 = (long)blockIdx.x * M_TILE;

    // phase 0: velocities tile -> LDS bf16, k padded to 32 with zeros
    for (int idx = tid; idx < M_TILE * 32; idx += THREADS) {
        int r = idx >> 5, c = idx & 31;
        float v = (c < IN_DIM) ? V[(row0 + r) * IN_DIM + c] : 0.0f;
        vlds[r][c] = (bf16_t)v;
    }
    __syncthreads();

    // phase 1: h1[m][n] = relu(V @ W1^T + b1), n in [wave*64, wave*64+64)
    {
        bf16x8 bv[4];
        #pragma unroll
        for (int mt = 0; mt < 4; ++mt)
            bv[mt] = *reinterpret_cast<const bf16x8*>(&vlds[mt * 16 + l16][quad * 8]);
        #pragma unroll
        for (int nt = 0; nt < 4; ++nt) {
            int ntile = wave * 4 + nt;
            bf16x8 aw = *reinterpret_cast<const bf16x8*>(W1f + ntile * 512 + lane * 8);
            f32x4 bias = *reinterpret_cast<const f32x4*>(b1 + ntile * 16 + quad * 4);
            int n0 = ntile * 16 + quad * 4;
            #pragma unroll
            for (int mt = 0; mt < 4; ++mt) {
                f32x4 c = {0.0f, 0.0f, 0.0f, 0.0f};
                c = __builtin_amdgcn_mfma_f32_16x16x32_bf16(aw, bv[mt], c, 0, 0, 0);
                bf16x4 pk;
                #pragma unroll
                for (int r = 0; r < 4; ++r) {
                    float v = c[r] + bias[r];
                    pk[r] = (bf16_t)(v > 0.0f ? v : 0.0f);
                }
                int m = mt * 16 + l16;
                *reinterpret_cast<bf16x4*>(&h[m][n0 ^ sx]) = pk;
            }
        }
    }
    __syncthreads();

    // phase 2: h2 = relu(h1 @ W2^T + b2). Per wave: M=64, N=64, K=512.
    // K-loop deliberately ROLLED (#pragma unroll 1): live set = acc(64, AGPR)
    // + bh(16) + aw(16) + addressing ~ 105 regs < 128 cap. The fully-unrolled
    // version hoisted 64 loads and spilled to scratch (round 2: 119 MB
    // WRITE_SIZE). Latency cover is TLP: 16 waves/CU, 16 indep MFMAs/iter.
    {
        f32x4 acc[4][4];
        #pragma unroll
        for (int mt = 0; mt < 4; ++mt)
            #pragma unroll
            for (int nt = 0; nt < 4; ++nt)
                acc[mt][nt] = (f32x4){0.0f, 0.0f, 0.0f, 0.0f};

        const bf16_t* w2p = W2f + (wave * 4) * 512 + lane * 8;  // + nt*512 + ks*16384

        #pragma unroll 1
        for (int ks = 0; ks < 16; ++ks) {
            const bf16_t* wk = w2p + ks * 16384;
            bf16x8 aw[4];
            #pragma unroll
            for (int nt = 0; nt < 4; ++nt)
                aw[nt] = *reinterpret_cast<const bf16x8*>(wk + nt * 512);
            bf16x8 bh[4];
            #pragma unroll
            for (int mt = 0; mt < 4; ++mt)
                bh[mt] = *reinterpret_cast<const bf16x8*>(
                    &h[mt * 16 + l16][(ks * 32 + quad * 8) ^ sx]);
            #pragma unroll
            for (int mt = 0; mt < 4; ++mt)
                #pragma unroll
                for (int nt = 0; nt < 4; ++nt)
                    acc[mt][nt] = __builtin_amdgcn_mfma_f32_16x16x32_bf16(aw[nt], bh[mt], acc[mt][nt], 0, 0, 0);
        }
        __syncthreads();  // all reads of h1 complete before overwrite

        #pragma unroll
        for (int nt = 0; nt < 4; ++nt) {
            int ntile = wave * 4 + nt;
            f32x4 bias = *reinterpret_cast<const f32x4*>(b2 + ntile * 16 + quad * 4);
            int n0 = ntile * 16 + quad * 4;
            #pragma unroll
            for (int mt = 0; mt < 4; ++mt) {
                bf16x4 pk;
                #pragma unroll
                for (int r = 0; r < 4; ++r) {
                    float v = acc[mt][nt][r] + bias[r];
                    pk[r] = (bf16_t)(v > 0.0f ? v : 0.0f);
                }
                int m = mt * 16 + l16;
                *reinterpret_cast<bf16x4*>(&h[m][n0 ^ sx]) = pk;
            }
        }
    }
    __syncthreads();

    // phase 3: out = h2 @ W3^T + b3, then loss. 8 jobs = 4 mt x 2 ot = 8 waves.
    {
        const int mt = wave >> 1;
        const int ot = wave & 1;
        const int o0 = ot * 16 + quad * 4;
        const long grow = row0 + mt * 16 + l16;

        // hoist gt/b3 loads above the K-loop (hide latency under MFMAs)
        float g[4], b3v[4];
        #pragma unroll
        for (int r = 0; r < 4; ++r) {
            bool v = (o0 + r) < OUT_DIM;
            g[r]   = v ? gt[grow * OUT_DIM + o0 + r] : -10000.0f;
            b3v[r] = v ? b3[o0 + r] : 0.0f;
        }

        f32x4 acc3a = {0.0f, 0.0f, 0.0f, 0.0f};
        f32x4 acc3b = {0.0f, 0.0f, 0.0f, 0.0f};
        const int rr = mt * 16 + l16;
        #pragma unroll
        for (int ks = 0; ks < 16; ks += 2) {
            bf16x8 bh0 = *reinterpret_cast<const bf16x8*>(&h[rr][(ks * 32 + quad * 8) ^ sx]);
            bf16x8 bh1 = *reinterpret_cast<const bf16x8*>(&h[rr][((ks + 1) * 32 + quad * 8) ^ sx]);
            bf16x8 aw0 = *reinterpret_cast<const bf16x8*>(W3f + (ks * 2 + ot) * 512 + lane * 8);
            bf16x8 aw1 = *reinterpret_cast<const bf16x8*>(W3f + ((ks + 1) * 2 + ot) * 512 + lane * 8);
            acc3a = __builtin_amdgcn_mfma_f32_16x16x32_bf16(aw0, bh0, acc3a, 0, 0, 0);
            acc3b = __builtin_amdgcn_mfma_f32_16x16x32_bf16(aw1, bh1, acc3b, 0, 0, 0);
        }

        float num = 0.0f, den = 0.0f;
        #pragma unroll
        for (int r = 0; r < 4; ++r) {
            if ((o0 + r) < OUT_DIM) {
                float pred = acc3a[r] + acc3b[r] + b3v[r];
                if (g[r] > -5000.0f) {
                    float w = (floorf(pred * 2.0f) == floorf(g[r] * 2.0f)) ? 0.5f : 1.0f;
                    num += fabsf(pred * w - g[r] * w);
                    den += 1.0f;
                }
            }
        }
        #pragma unroll
        for (int off = 32; off > 0; off >>= 1) {
            num += __shfl_down(num, off);
            den += __shfl_down(den, off);
        }
        if (lane == 0) { redbuf[wave * 2] = num; redbuf[wave * 2 + 1] = den; }
    }
    __syncthreads();
    if (tid == 0) {
        float n8 = 0.0f, d8 = 0.0f;
        #pragma unroll
        for (int w = 0; w < 8; ++w) { n8 += redbuf[w * 2]; d8 += redbuf[w * 2 + 1]; }
        atomicAdd(accum, n8);
        atomicAdd(accum + 1, d8);
    }
}

__global__ void finalize_kernel(const float* __restrict__ accum, float* __restrict__ out) {
    if (threadIdx.x == 0) out[0] = accum[0] / accum[1];
}

extern "C" void kernel_launch(void* const* d_in, const int* in_sizes, int n_in,
                              void* d_out, int out_size, void* d_ws, size_t ws_size,
                              hipStream_t stream) {
    const float* V  = (const float*)d_in[0];
    const float* gt = (const float*)d_in[1];
    const float* W1 = (const float*)d_in[2];
    const float* b1 = (const float*)d_in[3];
    const float* W2 = (const float*)d_in[4];
    const float* b2 = (const float*)d_in[5];
    const float* W3 = (const float*)d_in[6];
    const float* b3 = (const float*)d_in[7];
    float* out = (float*)d_out;

    char* ws = (char*)d_ws;
    float* accum = (float*)ws;                                       // 2 floats
    bf16_t* W2f = (bf16_t*)(ws + 16);                                // 512 KB
    bf16_t* W1f = (bf16_t*)(ws + 16 + 512 * 512 * 2);                // 32 KB
    bf16_t* W3f = (bf16_t*)(ws + 16 + 512 * 512 * 2 + 32 * 512 * 2); // 32 KB

    int Brows = in_sizes[0] / IN_DIM;   // 131072
    int grid = Brows / M_TILE;          // 2048

    prep_kernel<<<576, 512, 0, stream>>>(W1, W2, W3, W1f, W2f, W3f, accum);
    fused_kernel<<<grid, THREADS, 0, stream>>>(V, gt, b1, b2, b3, W1f, W2f, W3f, accum);
    finalize_kernel<<<1, 64, 0, stream>>>(accum, out);
}

// Round 4
// 193.446 us; speedup vs baseline: 1.1513x; 1.0059x over previous
//
#include <hip/hip_runtime.h>
#include <hip/hip_bf16.h>

typedef __bf16 bf16_t;
typedef __bf16 bf16x4 __attribute__((ext_vector_type(4)));
typedef __bf16 bf16x8 __attribute__((ext_vector_type(8)));
typedef float f32x4 __attribute__((ext_vector_type(4)));

#define IN_DIM 21
#define HID 512
#define OUT_DIM 21
#define M_TILE 128    // 128 rows/block -> 1024 blocks: halves total W2f L2/L3 traffic vs 64
#define THREADS 1024  // 16 waves: wave = (m-half, n-group); 4 waves/SIMD, 1 block/CU (LDS 141 KB)

// XOR swizzle in element units: flips col bits 3..5 with row low bits.
// For all h accesses row&7 == l16&7, so the XOR term is a per-lane constant.
// b128 reads / b64 writes stay aligned and uniformly spread over banks.
__device__ __forceinline__ int swz(int row, int col) {
    return col ^ ((row & 7) << 3);
}

// ---- prep: convert weights fp32 -> bf16 *fragment-major* layouts in ws ----
// Fragment for 16x16x32 mfma: element (outer = tile*16 + (lane&15),
// k = k0 + (lane>>4)*8 + j) stored at frag_base + lane*8 + j.
// W2f: [kstep(16)][ntile(32)][512]   W1f: [ntile(32)][512] (k>=21 zero)
// W3f: [kstep(16)][otile(2)][512]    (o>=21 zero)
__global__ void prep_kernel(const float* __restrict__ W1, const float* __restrict__ W2,
                            const float* __restrict__ W3,
                            bf16_t* __restrict__ W1f, bf16_t* __restrict__ W2f,
                            bf16_t* __restrict__ W3f, float* __restrict__ accum) {
    if (blockIdx.x == 0 && threadIdx.x == 0) {
        accum[0] = 0.0f; accum[1] = 0.0f;
        ((unsigned*)accum)[2] = 0u;   // last-block ticket
    }
    int i = blockIdx.x * blockDim.x + threadIdx.x;
    int stride = gridDim.x * blockDim.x;
    const int NW2 = HID * HID;     // 262144
    const int NW1 = 32 * 512;      // 16384
    const int NW3 = 16 * 2 * 512;  // 16384
    for (; i < NW2 + NW1 + NW3; i += stride) {
        if (i < NW2) {
            int j = i & 7, lane = (i >> 3) & 63, ntile = (i >> 9) & 31, kstep = i >> 14;
            int n = ntile * 16 + (lane & 15);
            int k = kstep * 32 + (lane >> 4) * 8 + j;
            W2f[i] = (bf16_t)W2[n * HID + k];
        } else if (i < NW2 + NW1) {
            int t = i - NW2;
            int j = t & 7, lane = (t >> 3) & 63, ntile = t >> 9;
            int n = ntile * 16 + (lane & 15);
            int k = (lane >> 4) * 8 + j;
            W1f[t] = (k < IN_DIM) ? (bf16_t)W1[n * IN_DIM + k] : (bf16_t)0.0f;
        } else {
            int t = i - NW2 - NW1;
            int j = t & 7, lane = (t >> 3) & 63, ot = (t >> 9) & 1, kstep = t >> 10;
            int o = ot * 16 + (lane & 15);
            int k = kstep * 32 + (lane >> 4) * 8 + j;
            W3f[t] = (o < OUT_DIM) ? (bf16_t)W3[o * HID + k] : (bf16_t)0.0f;
        }
    }
}

// ---- fused MLP + loss ----
// Operand-swapped mfma everywhere: D = A(W-frag) * B(activation^T-frag):
// D col = lane&15 = batch-row m, D row = quad*4+r = feature n -> each lane's 4
// acc values are 4 consecutive features of one row: b64 LDS epilogue writes.
__global__ __launch_bounds__(THREADS, 4)  // 4 waves/EU -> reg cap 128 (64 arch + 64 acc)
void fused_kernel(const float* __restrict__ V, const float* __restrict__ gt,
                  const float* __restrict__ b1, const float* __restrict__ b2,
                  const float* __restrict__ b3,
                  const bf16_t* __restrict__ W1f, const bf16_t* __restrict__ W2f,
                  const bf16_t* __restrict__ W3f, float* __restrict__ accum,
                  float* __restrict__ out) {
    __shared__ __align__(16) bf16_t vlds[M_TILE][40];  // stride 80 B: 2-way max on b128 reads
    __shared__ __align__(16) bf16_t h[M_TILE][HID];    // single buffer: h1, then h2 in-place
    __shared__ float redbuf[32];

    const int tid  = threadIdx.x;
    const int wave = tid >> 6;       // 0..15
    const int lane = tid & 63;
    const int quad = lane >> 4;
    const int l16  = lane & 15;
    const int mh   = wave >> 3;      // m-half: rows mh*64 .. mh*64+63
    const int ng   = wave & 7;       // n-group: ntiles ng*4 .. ng*4+3
    const int sx   = (l16 & 7) << 3; // per-lane swizzle XOR constant
    const long row0 = (long)blockIdx.x * M_TILE;

    // Issue the first W2f fragment group NOW: it completes during phases 0-1,
    // so phase 2's first iteration starts with operands already in regs.
    const bf16_t* w2p = W2f + ng * 4 * 512 + lane * 8;  // + nt*512 + ks*16384
    bf16x8 awA[4], awB[4];
    #pragma unroll
    for (int nt = 0; nt < 4; ++nt)
        awA[nt] = *reinterpret_cast<const bf16x8*>(w2p + nt * 512);

    // phase 0: velocities tile -> LDS bf16, k padded to 32 with zeros
    for (int idx = tid; idx < M_TILE * 32; idx += THREADS) {
        int r = idx >> 5, c = idx & 31;
        float v = (c < IN_DIM) ? V[(row0 + r) * IN_DIM + c] : 0.0f;
        vlds[r][c] = (bf16_t)v;
    }
    __syncthreads();

    // phase 1: h1[m][n] = relu(V @ W1^T + b1); wave covers (mh rows) x (ng cols)
    {
        bf16x8 bv[4];
        #pragma unroll
        for (int mt = 0; mt < 4; ++mt)
            bv[mt] = *reinterpret_cast<const bf16x8*>(&vlds[mh * 64 + mt * 16 + l16][quad * 8]);
        #pragma unroll
        for (int nt = 0; nt < 4; ++nt) {
            int ntile = ng * 4 + nt;
            bf16x8 aw = *reinterpret_cast<const bf16x8*>(W1f + ntile * 512 + lane * 8);
            f32x4 bias = *reinterpret_cast<const f32x4*>(b1 + ntile * 16 + quad * 4);
            int n0 = ntile * 16 + quad * 4;
            #pragma unroll
            for (int mt = 0; mt < 4; ++mt) {
                f32x4 c = {0.0f, 0.0f, 0.0f, 0.0f};
                c = __builtin_amdgcn_mfma_f32_16x16x32_bf16(aw, bv[mt], c, 0, 0, 0);
                bf16x4 pk;
                #pragma unroll
                for (int r = 0; r < 4; ++r) {
                    float v = c[r] + bias[r];
                    pk[r] = (bf16_t)(v > 0.0f ? v : 0.0f);
                }
                int m = mh * 64 + mt * 16 + l16;
                *reinterpret_cast<bf16x4*>(&h[m][n0 ^ sx]) = pk;
            }
        }
    }
    __syncthreads();

    // phase 2: h2 = relu(h1 @ W2^T + b2). Per wave: M=64 (its half), N=64, K=512.
    // K-loop ROLLED (#pragma unroll 1) to prevent the full-hoist spill (round 2:
    // 119 MB scratch). Manual depth-1 ping-pong on the W2f loads hides L2/L3
    // latency under the 16-MFMA burst. Live ~ 64 acc + 32 aw + 16 bh + addr < 128.
    {
        f32x4 acc[4][4];
        #pragma unroll
        for (int mt = 0; mt < 4; ++mt)
            #pragma unroll
            for (int nt = 0; nt < 4; ++nt)
                acc[mt][nt] = (f32x4){0.0f, 0.0f, 0.0f, 0.0f};

        #pragma unroll 1
        for (int ks = 0; ks < 16; ks += 2) {
            // prefetch aw for ks+1
            #pragma unroll
            for (int nt = 0; nt < 4; ++nt)
                awB[nt] = *reinterpret_cast<const bf16x8*>(w2p + (ks + 1) * 16384 + nt * 512);
            {
                bf16x8 bh[4];
                #pragma unroll
                for (int mt = 0; mt < 4; ++mt)
                    bh[mt] = *reinterpret_cast<const bf16x8*>(
                        &h[mh * 64 + mt * 16 + l16][(ks * 32 + quad * 8) ^ sx]);
                #pragma unroll
                for (int mt = 0; mt < 4; ++mt)
                    #pragma unroll
                    for (int nt = 0; nt < 4; ++nt)
                        acc[mt][nt] = __builtin_amdgcn_mfma_f32_16x16x32_bf16(awA[nt], bh[mt], acc[mt][nt], 0, 0, 0);
            }
            // prefetch aw for ks+2 (ks=14 overreads into W1f region of ws: harmless)
            #pragma unroll
            for (int nt = 0; nt < 4; ++nt)
                awA[nt] = *reinterpret_cast<const bf16x8*>(w2p + (ks + 2) * 16384 + nt * 512);
            {
                bf16x8 bh[4];
                #pragma unroll
                for (int mt = 0; mt < 4; ++mt)
                    bh[mt] = *reinterpret_cast<const bf16x8*>(
                        &h[mh * 64 + mt * 16 + l16][((ks + 1) * 32 + quad * 8) ^ sx]);
                #pragma unroll
                for (int mt = 0; mt < 4; ++mt)
                    #pragma unroll
                    for (int nt = 0; nt < 4; ++nt)
                        acc[mt][nt] = __builtin_amdgcn_mfma_f32_16x16x32_bf16(awB[nt], bh[mt], acc[mt][nt], 0, 0, 0);
            }
        }
        __syncthreads();  // all reads of h1 complete before overwrite

        #pragma unroll
        for (int nt = 0; nt < 4; ++nt) {
            int ntile = ng * 4 + nt;
            f32x4 bias = *reinterpret_cast<const f32x4*>(b2 + ntile * 16 + quad * 4);
            int n0 = ntile * 16 + quad * 4;
            #pragma unroll
            for (int mt = 0; mt < 4; ++mt) {
                bf16x4 pk;
                #pragma unroll
                for (int r = 0; r < 4; ++r) {
                    float v = acc[mt][nt][r] + bias[r];
                    pk[r] = (bf16_t)(v > 0.0f ? v : 0.0f);
                }
                int m = mh * 64 + mt * 16 + l16;
                *reinterpret_cast<bf16x4*>(&h[m][n0 ^ sx]) = pk;
            }
        }
    }
    __syncthreads();

    // phase 3: out = h2 @ W3^T + b3, then loss. 16 jobs = 8 mt x 2 ot = 16 waves.
    {
        const int mt = wave >> 1;
        const int ot = wave & 1;
        const int o0 = ot * 16 + quad * 4;
        const long grow = row0 + mt * 16 + l16;

        // hoist gt/b3 loads above the K-loop (hide latency under MFMAs)
        float g[4], b3v[4];
        #pragma unroll
        for (int r = 0; r < 4; ++r) {
            bool v = (o0 + r) < OUT_DIM;
            g[r]   = v ? gt[grow * OUT_DIM + o0 + r] : -10000.0f;
            b3v[r] = v ? b3[o0 + r] : 0.0f;
        }

        f32x4 acc3a = {0.0f, 0.0f, 0.0f, 0.0f};
        f32x4 acc3b = {0.0f, 0.0f, 0.0f, 0.0f};
        const int rr = mt * 16 + l16;
        #pragma unroll
        for (int ks = 0; ks < 16; ks += 2) {
            bf16x8 bh0 = *reinterpret_cast<const bf16x8*>(&h[rr][(ks * 32 + quad * 8) ^ sx]);
            bf16x8 bh1 = *reinterpret_cast<const bf16x8*>(&h[rr][((ks + 1) * 32 + quad * 8) ^ sx]);
            bf16x8 aw0 = *reinterpret_cast<const bf16x8*>(W3f + (ks * 2 + ot) * 512 + lane * 8);
            bf16x8 aw1 = *reinterpret_cast<const bf16x8*>(W3f + ((ks + 1) * 2 + ot) * 512 + lane * 8);
            acc3a = __builtin_amdgcn_mfma_f32_16x16x32_bf16(aw0, bh0, acc3a, 0, 0, 0);
            acc3b = __builtin_amdgcn_mfma_f32_16x16x32_bf16(aw1, bh1, acc3b, 0, 0, 0);
        }

        float num = 0.0f, den = 0.0f;
        #pragma unroll
        for (int r = 0; r < 4; ++r) {
            if ((o0 + r) < OUT_DIM) {
                float pred = acc3a[r] + acc3b[r] + b3v[r];
                if (g[r] > -5000.0f) {
                    float w = (floorf(pred * 2.0f) == floorf(g[r] * 2.0f)) ? 0.5f : 1.0f;
                    num += fabsf(pred * w - g[r] * w);
                    den += 1.0f;
                }
            }
        }
        #pragma unroll
        for (int off = 32; off > 0; off >>= 1) {
            num += __shfl_down(num, off);
            den += __shfl_down(den, off);
        }
        if (lane == 0) { redbuf[wave * 2] = num; redbuf[wave * 2 + 1] = den; }
    }
    __syncthreads();
    if (tid == 0) {
        float nB = 0.0f, dB = 0.0f;
        #pragma unroll
        for (int w = 0; w < 16; ++w) { nB += redbuf[w * 2]; dB += redbuf[w * 2 + 1]; }
        atomicAdd(accum, nB);
        atomicAdd(accum + 1, dB);
        __threadfence();
        unsigned prev = atomicAdd((unsigned*)(accum + 2), 1u);
        if (prev == gridDim.x - 1) {   // last block finalizes (saves a kernel launch)
            __threadfence();
            float num = __hip_atomic_load(accum,     __ATOMIC_RELAXED, __HIP_MEMORY_SCOPE_AGENT);
            float den = __hip_atomic_load(accum + 1, __ATOMIC_RELAXED, __HIP_MEMORY_SCOPE_AGENT);
            out[0] = num / den;
        }
    }
}

extern "C" void kernel_launch(void* const* d_in, const int* in_sizes, int n_in,
                              void* d_out, int out_size, void* d_ws, size_t ws_size,
                              hipStream_t stream) {
    const float* V  = (const float*)d_in[0];
    const float* gt = (const float*)d_in[1];
    const float* W1 = (const float*)d_in[2];
    const float* b1 = (const float*)d_in[3];
    const float* W2 = (const float*)d_in[4];
    const float* b2 = (const float*)d_in[5];
    const float* W3 = (const float*)d_in[6];
    const float* b3 = (const float*)d_in[7];
    float* out = (float*)d_out;

    char* ws = (char*)d_ws;
    float* accum = (float*)ws;                                       // 2 floats + 1 ticket
    bf16_t* W2f = (bf16_t*)(ws + 16);                                // 512 KB
    bf16_t* W1f = (bf16_t*)(ws + 16 + 512 * 512 * 2);                // 32 KB
    bf16_t* W3f = (bf16_t*)(ws + 16 + 512 * 512 * 2 + 32 * 512 * 2); // 32 KB

    int Brows = in_sizes[0] / IN_DIM;   // 131072
    int grid = Brows / M_TILE;          // 1024

    prep_kernel<<<576, 512, 0, stream>>>(W1, W2, W3, W1f, W2f, W3f, accum);
    fused_kernel<<<grid, THREADS, 0, stream>>>(V, gt, b1, b2, b3, W1f, W2f, W3f, accum, out);
}